// Round 1
// baseline (400.833 us; speedup 1.0000x reference)
//
#include <hip/hip_runtime.h>
#include <hip/hip_bf16.h>
#include <stdint.h>

// NBEATS MoE block, dense-expert bf16 MFMA implementation (round 1).
// Pipeline:
//   1) gate_cast_k : per-row LayerNorm (fp32) -> gate logits (512x8 matvec) ->
//                    top-2 + softmax weights; also casts x rows to bf16.
//   2) transpose_cast_k : fp32 weights -> bf16, transposed to [N][K] (B^T form)
//                    so GEMM B-fragments are contiguous ds_read_b128.
//   3) gemm_k<RELU,FINAL> : 128x128 tile, 4 waves (2x2), each wave 4x4 of
//                    mfma_f32_16x16x32_bf16. BK=32 single-buffered LDS staged
//                    via global_load_lds width=16 (m97 pattern, unpadded LDS).
//                    FINAL fuses top-2 gate combine via atomicAdd into the
//                    split backcast/forecast output.

#define B_ROWS 8192
#define I_DIM  512
#define H_DIM  512
#define E_NUM  8
#define T_DIM  608
#define T_PAD  640   // Wout^T rows padded to tile multiple; pad cols discarded

typedef unsigned short ushort_t;
typedef __attribute__((ext_vector_type(8))) __bf16 bf16x8;
typedef __attribute__((ext_vector_type(8))) unsigned short ushort8;
typedef __attribute__((ext_vector_type(4))) float floatx4;

__device__ __forceinline__ void gload_lds16(const void* g, void* l) {
  // async global->LDS, 16B per lane; LDS dest = wave-uniform base + lane*16
  __builtin_amdgcn_global_load_lds(
      (const __attribute__((address_space(1))) unsigned int*)g,
      (__attribute__((address_space(3))) unsigned int*)l, 16, 0, 0);
}

__device__ __forceinline__ ushort_t f2bf(float v) {
  __hip_bfloat16 h = __float2bfloat16(v);
  return __builtin_bit_cast(unsigned short, h);
}

// ---------------------------------------------------------------- gating ----
// one wave per row: LN (fp32) -> logits (8) -> top2 softmax; cast x to bf16
__global__ __launch_bounds__(256) void gate_cast_k(
    const float* __restrict__ x, const float* __restrict__ gamma,
    const float* __restrict__ beta, const float* __restrict__ Wg,
    ushort_t* __restrict__ xb, int2* __restrict__ gidx, float2* __restrict__ gw)
{
  const int row  = (blockIdx.x * blockDim.x + threadIdx.x) >> 6;
  const int lane = threadIdx.x & 63;
  const float* xr = x + (size_t)row * I_DIM + lane * 8;
  float4 a = *(const float4*)(xr);
  float4 b = *(const float4*)(xr + 4);
  float xs[8] = {a.x, a.y, a.z, a.w, b.x, b.y, b.z, b.w};

  float s = 0.f;
#pragma unroll
  for (int j = 0; j < 8; ++j) s += xs[j];
#pragma unroll
  for (int off = 32; off; off >>= 1) s += __shfl_xor(s, off);
  const float mu = s * (1.0f / I_DIM);

  float vs = 0.f;
#pragma unroll
  for (int j = 0; j < 8; ++j) { float d = xs[j] - mu; vs += d * d; }
#pragma unroll
  for (int off = 32; off; off >>= 1) vs += __shfl_xor(vs, off);
  const float rstd = rsqrtf(vs * (1.0f / I_DIM) + 1e-5f);

  float lg[8] = {0.f, 0.f, 0.f, 0.f, 0.f, 0.f, 0.f, 0.f};
  const float* gmr = gamma + lane * 8;
  const float* btr = beta + lane * 8;
#pragma unroll
  for (int j = 0; j < 8; ++j) {
    const float y = (xs[j] - mu) * rstd * gmr[j] + btr[j];
    const float* wr = Wg + (size_t)(lane * 8 + j) * E_NUM;
#pragma unroll
    for (int e = 0; e < 8; ++e) lg[e] += y * wr[e];
  }
#pragma unroll
  for (int e = 0; e < 8; ++e)
#pragma unroll
    for (int off = 32; off; off >>= 1) lg[e] += __shfl_xor(lg[e], off);

  // store bf16 row (16B per lane)
  ushort8 o;
#pragma unroll
  for (int j = 0; j < 8; ++j) o[j] = f2bf(xs[j]);
  *(ushort8*)(xb + (size_t)row * I_DIM + lane * 8) = o;

  if (lane == 0) {
    int i0 = 0; float b0 = lg[0];
#pragma unroll
    for (int e = 1; e < 8; ++e) if (lg[e] > b0) { b0 = lg[e]; i0 = e; }
    int i1 = -1; float b1 = -3.4e38f;
#pragma unroll
    for (int e = 0; e < 8; ++e) if (e != i0 && lg[e] > b1) { b1 = lg[e]; i1 = e; }
    const float w0 = 1.0f / (1.0f + __expf(b1 - b0));  // softmax over {b0,b1}
    gidx[row] = make_int2(i0, i1);
    gw[row] = make_float2(w0, 1.0f - w0);
  }
}

// ------------------------------------------------- weight transpose+cast ----
// src fp32 [batch][R][C] -> dst bf16 [batch][C][R]  (B^T layout for GEMM)
__global__ __launch_bounds__(256) void transpose_cast_k(
    const float* __restrict__ src, ushort_t* __restrict__ dst,
    int R, int C, size_t srcBStr, size_t dstBStr)
{
  __shared__ float tile[32][33];
  src += (size_t)blockIdx.z * srcBStr;
  dst += (size_t)blockIdx.z * dstBStr;
  const int c0 = blockIdx.x * 32, r0 = blockIdx.y * 32;
  const int tx = threadIdx.x, ty = threadIdx.y;  // block (32,8)
#pragma unroll
  for (int i = 0; i < 4; ++i)
    tile[ty + i * 8][tx] = src[(size_t)(r0 + ty + i * 8) * C + c0 + tx];
  __syncthreads();
#pragma unroll
  for (int i = 0; i < 4; ++i) {
    const int c = c0 + ty + i * 8;
    if (c < C) dst[(size_t)c * R + r0 + tx] = f2bf(tile[tx][ty + i * 8]);
  }
}

// ------------------------------------------------------------------ GEMM ----
// C[128x128 tile] = A[M x 512] (bf16 rowmaj) x B^T[N x 512] (bf16 rowmaj)
// grid = (M/128, Ntiles, experts). Mid: bf16 out (opt relu). Final: gated
// atomicAdd into split fp32 output.
template <bool RELU, bool FINAL>
__global__ __launch_bounds__(256) void gemm_k(
    const ushort_t* __restrict__ A, size_t aEStr,
    const ushort_t* __restrict__ B, size_t bEStr, int e0,
    ushort_t* __restrict__ Z, size_t zEStr,
    float* __restrict__ out, const int2* __restrict__ gidx,
    const float2* __restrict__ gw)
{
  constexpr int K = 512;
  __shared__ ushort_t lA[128 * 32];
  __shared__ ushort_t lB[128 * 32];
  __shared__ float wrow[128];

  const int tid = threadIdx.x, wid = tid >> 6, lane = tid & 63;
  const int bm0 = blockIdx.x * 128, bn0 = blockIdx.y * 128, e = blockIdx.z;

  const ushort_t* Ab = A + (size_t)e * aEStr + (size_t)bm0 * K;
  const ushort_t* Bb = B + (size_t)(e0 + e) * bEStr + (size_t)bn0 * K;

  // staging: wave w covers rows w*16+(lane>>2), 16B chunk (lane&3); +64 rows 2nd issue
  const int sr = wid * 16 + (lane >> 2);
  const int sc = (lane & 3) * 8;
  const ushort_t* ga = Ab + (size_t)sr * K + sc;
  const ushort_t* gb = Bb + (size_t)sr * K + sc;
  ushort_t* la = lA + wid * 512;
  ushort_t* lb = lB + wid * 512;

  floatx4 acc[4][4] = {};
  const int wm = (wid >> 1) * 64, wn = (wid & 1) * 64;
  const int fr = lane & 15, q = lane >> 4;

  for (int k0 = 0; k0 < K; k0 += 32) {
    gload_lds16(ga + k0, la);
    gload_lds16(ga + 64 * K + k0, la + 64 * 32);
    gload_lds16(gb + k0, lb);
    gload_lds16(gb + 64 * K + k0, lb + 64 * 32);
    __syncthreads();

    bf16x8 af[4], bfr[4];
#pragma unroll
    for (int mi = 0; mi < 4; ++mi)
      af[mi] = *(const bf16x8*)(lA + (wm + mi * 16 + fr) * 32 + q * 8);
#pragma unroll
    for (int ni = 0; ni < 4; ++ni)
      bfr[ni] = *(const bf16x8*)(lB + (wn + ni * 16 + fr) * 32 + q * 8);
#pragma unroll
    for (int mi = 0; mi < 4; ++mi)
#pragma unroll
      for (int ni = 0; ni < 4; ++ni)
        acc[mi][ni] = __builtin_amdgcn_mfma_f32_16x16x32_bf16(
            af[mi], bfr[ni], acc[mi][ni], 0, 0, 0);
    __syncthreads();
  }

  if (!FINAL) {
    // C/D layout: col = lane&15, row = (lane>>4)*4 + reg (m89-verified)
    ushort_t* Zb = Z + (size_t)e * zEStr + (size_t)bm0 * H_DIM + bn0;
#pragma unroll
    for (int mi = 0; mi < 4; ++mi)
#pragma unroll
      for (int r = 0; r < 4; ++r) {
        const int row = wm + mi * 16 + q * 4 + r;
        ushort_t* zr = Zb + (size_t)row * H_DIM + wn + fr;
#pragma unroll
        for (int ni = 0; ni < 4; ++ni) {
          float v = acc[mi][ni][r];
          if (RELU) v = fmaxf(v, 0.0f);
          zr[ni * 16] = f2bf(v);
        }
      }
  } else {
    const int ge = e0 + e;
    if (tid < 128) {
      const int brow = bm0 + tid;
      const int2 ii = gidx[brow];
      const float2 ww = gw[brow];
      float w = 0.0f;
      if (ii.x == ge) w = ww.x;
      else if (ii.y == ge) w = ww.y;
      wrow[tid] = w;
    }
    __syncthreads();
#pragma unroll
    for (int mi = 0; mi < 4; ++mi)
#pragma unroll
      for (int r = 0; r < 4; ++r) {
        const int row = wm + mi * 16 + q * 4 + r;
        const float w = wrow[row];
        if (w != 0.0f) {
          const size_t bglob = bm0 + row;
#pragma unroll
          for (int ni = 0; ni < 4; ++ni) {
            const int col = bn0 + wn + ni * 16 + fr;
            if (col < T_DIM) {
              const float v = acc[mi][ni][r] * w;
              float* dst = (col < I_DIM)
                  ? out + bglob * I_DIM + col
                  : out + (size_t)B_ROWS * I_DIM + bglob * (T_DIM - I_DIM) +
                        (col - I_DIM);
              atomicAdd(dst, v);
            }
          }
        }
      }
  }
}

// ---------------------------------------------------------------- launch ----
extern "C" void kernel_launch(void* const* d_in, const int* in_sizes, int n_in,
                              void* d_out, int out_size, void* d_ws,
                              size_t ws_size, hipStream_t stream) {
  const float* x     = (const float*)d_in[0];
  const float* gamma = (const float*)d_in[1];
  const float* beta  = (const float*)d_in[2];
  const float* Wg    = (const float*)d_in[3];
  const float* W0    = (const float*)d_in[4];
  const float* Wmid  = (const float*)d_in[5];
  const float* Wout  = (const float*)d_in[6];
  float* out = (float*)d_out;

  char* ws = (char*)d_ws;
  size_t off = 0;
  auto alloc = [&](size_t bytes) -> char* {
    char* p = ws + off;
    off += (bytes + 255) & ~(size_t)255;
    return p;
  };

  const size_t SQ = (size_t)H_DIM * H_DIM;  // 512*512
  ushort_t* xb    = (ushort_t*)alloc((size_t)B_ROWS * I_DIM * 2);
  ushort_t* W0t   = (ushort_t*)alloc((size_t)E_NUM * SQ * 2);
  ushort_t* Wmidt = (ushort_t*)alloc((size_t)3 * E_NUM * SQ * 2);
  ushort_t* Woutt = (ushort_t*)alloc((size_t)E_NUM * T_PAD * H_DIM * 2);
  int2*   gidx = (int2*)alloc((size_t)B_ROWS * sizeof(int2));
  float2* gwv  = (float2*)alloc((size_t)B_ROWS * sizeof(float2));

  const size_t zPerE = (size_t)B_ROWS * H_DIM;  // elements, per expert
  const size_t needFull = off + 2 * ((size_t)E_NUM * zPerE * 2 + 256);
  const int EB = (ws_size >= needFull) ? E_NUM : 1;  // expert batch per pass
  ushort_t* z0 = (ushort_t*)alloc((size_t)EB * zPerE * 2);
  ushort_t* z1 = (ushort_t*)alloc((size_t)EB * zPerE * 2);

  hipMemsetAsync(d_out, 0, (size_t)out_size * sizeof(float), stream);

  gate_cast_k<<<dim3(B_ROWS / 4), 256, 0, stream>>>(x, gamma, beta, Wg, xb,
                                                    gidx, gwv);
  transpose_cast_k<<<dim3(16, 16, 8), dim3(32, 8), 0, stream>>>(
      W0, W0t, 512, 512, SQ, SQ);
  transpose_cast_k<<<dim3(16, 16, 24), dim3(32, 8), 0, stream>>>(
      Wmid, Wmidt, 512, 512, SQ, SQ);
  transpose_cast_k<<<dim3(19, 16, 8), dim3(32, 8), 0, stream>>>(
      Wout, Woutt, 512, 608, (size_t)512 * 608, (size_t)T_PAD * 512);

  for (int e0 = 0; e0 < E_NUM; e0 += EB) {
    dim3 gmid(B_ROWS / 128, H_DIM / 128, EB);
    dim3 gfin(B_ROWS / 128, T_PAD / 128, EB);
    // z0 = x @ W0 (no relu)
    gemm_k<false, false><<<gmid, 256, 0, stream>>>(
        xb, 0, W0t, SQ, e0, z0, zPerE, nullptr, nullptr, nullptr);
    // z1 = relu(z0 @ Wmid[0])
    gemm_k<true, false><<<gmid, 256, 0, stream>>>(
        z0, zPerE, Wmidt + 0 * E_NUM * SQ, SQ, e0, z1, zPerE, nullptr, nullptr,
        nullptr);
    // z0 = relu(z1 @ Wmid[1])
    gemm_k<true, false><<<gmid, 256, 0, stream>>>(
        z1, zPerE, Wmidt + 1 * E_NUM * SQ, SQ, e0, z0, zPerE, nullptr, nullptr,
        nullptr);
    // z1 = relu(z0 @ Wmid[2])
    gemm_k<true, false><<<gmid, 256, 0, stream>>>(
        z0, zPerE, Wmidt + 2 * E_NUM * SQ, SQ, e0, z1, zPerE, nullptr, nullptr,
        nullptr);
    // out += gate_w * (z1 @ Wout), split backcast/forecast
    gemm_k<false, true><<<gfin, 256, 0, stream>>>(
        z1, zPerE, Woutt, (size_t)T_PAD * H_DIM, e0, nullptr, 0, out, gidx,
        gwv);
  }
}

// Round 2
// 327.434 us; speedup vs baseline: 1.2242x; 1.2242x over previous
//
#include <hip/hip_runtime.h>
#include <hip/hip_bf16.h>
#include <stdint.h>

// NBEATS MoE block — round 2: routed top-2 grouped GEMM.
//   gate_cast_k : LN -> gate logits -> top2 softmax; casts x rows to bf16.
//   transpose_cast_k : fp32 weights -> bf16 B^T layout [E][N][K].
//   sched_k : single block; per-expert counts (ballot-scan), padded segment
//             starts, tile table (NT_MAX=136), rowmap/wmap assignment + pad
//             zeroing. Deterministic (no global atomics).
//   gemm_k<GATHER,RELU,FINAL> : m97-style 128x128 tile, 4 waves, 4x4
//             mfma_f32_16x16x32_bf16, BK=32, global_load_lds width=16.
//             GATHER: A rows indirected through rowmap (free: per-lane global
//             addresses computed once pre-loop). FINAL: scatter + gate-weight
//             combine via atomicAdd into split backcast/forecast output.

#define B_ROWS 8192
#define I_DIM  512
#define H_DIM  512
#define E_NUM  8
#define T_DIM  608
#define T_PAD  640
#define NT_MAX 136           // max tiles: 16384/128 + 8
#define NPAD   17408         // max padded gathered rows: 16384 + 8*127 -> pad

typedef unsigned short ushort_t;
typedef __attribute__((ext_vector_type(8))) __bf16 bf16x8;
typedef __attribute__((ext_vector_type(8))) unsigned short ushort8;
typedef __attribute__((ext_vector_type(4))) float floatx4;

__device__ __forceinline__ void gload_lds16(const void* g, void* l) {
  __builtin_amdgcn_global_load_lds(
      (const __attribute__((address_space(1))) unsigned int*)g,
      (__attribute__((address_space(3))) unsigned int*)l, 16, 0, 0);
}

__device__ __forceinline__ ushort_t f2bf(float v) {
  __hip_bfloat16 h = __float2bfloat16(v);
  return __builtin_bit_cast(unsigned short, h);
}

// ---------------------------------------------------------------- gating ----
__global__ __launch_bounds__(256) void gate_cast_k(
    const float* __restrict__ x, const float* __restrict__ gamma,
    const float* __restrict__ beta, const float* __restrict__ Wg,
    ushort_t* __restrict__ xb, int2* __restrict__ gidx, float2* __restrict__ gw)
{
  const int row  = (blockIdx.x * blockDim.x + threadIdx.x) >> 6;
  const int lane = threadIdx.x & 63;
  const float* xr = x + (size_t)row * I_DIM + lane * 8;
  float4 a = *(const float4*)(xr);
  float4 b = *(const float4*)(xr + 4);
  float xs[8] = {a.x, a.y, a.z, a.w, b.x, b.y, b.z, b.w};

  float s = 0.f;
#pragma unroll
  for (int j = 0; j < 8; ++j) s += xs[j];
#pragma unroll
  for (int off = 32; off; off >>= 1) s += __shfl_xor(s, off);
  const float mu = s * (1.0f / I_DIM);

  float vs = 0.f;
#pragma unroll
  for (int j = 0; j < 8; ++j) { float d = xs[j] - mu; vs += d * d; }
#pragma unroll
  for (int off = 32; off; off >>= 1) vs += __shfl_xor(vs, off);
  const float rstd = rsqrtf(vs * (1.0f / I_DIM) + 1e-5f);

  float lg[8] = {0.f, 0.f, 0.f, 0.f, 0.f, 0.f, 0.f, 0.f};
  const float* gmr = gamma + lane * 8;
  const float* btr = beta + lane * 8;
#pragma unroll
  for (int j = 0; j < 8; ++j) {
    const float y = (xs[j] - mu) * rstd * gmr[j] + btr[j];
    const float* wr = Wg + (size_t)(lane * 8 + j) * E_NUM;
#pragma unroll
    for (int e = 0; e < 8; ++e) lg[e] += y * wr[e];
  }
#pragma unroll
  for (int e = 0; e < 8; ++e)
#pragma unroll
    for (int off = 32; off; off >>= 1) lg[e] += __shfl_xor(lg[e], off);

  ushort8 o;
#pragma unroll
  for (int j = 0; j < 8; ++j) o[j] = f2bf(xs[j]);
  *(ushort8*)(xb + (size_t)row * I_DIM + lane * 8) = o;

  if (lane == 0) {
    int i0 = 0; float b0 = lg[0];
#pragma unroll
    for (int e = 1; e < 8; ++e) if (lg[e] > b0) { b0 = lg[e]; i0 = e; }
    int i1 = -1; float b1 = -3.4e38f;
#pragma unroll
    for (int e = 0; e < 8; ++e) if (e != i0 && lg[e] > b1) { b1 = lg[e]; i1 = e; }
    const float w0 = 1.0f / (1.0f + __expf(b1 - b0));
    gidx[row] = make_int2(i0, i1);
    gw[row] = make_float2(w0, 1.0f - w0);
  }
}

// ------------------------------------------------- weight transpose+cast ----
__global__ __launch_bounds__(256) void transpose_cast_k(
    const float* __restrict__ src, ushort_t* __restrict__ dst,
    int R, int C, size_t srcBStr, size_t dstBStr)
{
  __shared__ float tile[32][33];
  src += (size_t)blockIdx.z * srcBStr;
  dst += (size_t)blockIdx.z * dstBStr;
  const int c0 = blockIdx.x * 32, r0 = blockIdx.y * 32;
  const int tx = threadIdx.x, ty = threadIdx.y;
#pragma unroll
  for (int i = 0; i < 4; ++i)
    tile[ty + i * 8][tx] = src[(size_t)(r0 + ty + i * 8) * C + c0 + tx];
  __syncthreads();
#pragma unroll
  for (int i = 0; i < 4; ++i) {
    const int c = c0 + ty + i * 8;
    if (c < C) dst[(size_t)c * R + r0 + tx] = f2bf(tile[tx][ty + i * 8]);
  }
}

// ------------------------------------------------------------- scheduler ----
// one block, 8 waves; wave e owns expert e. Deterministic ballot-scan ranking.
__global__ __launch_bounds__(512) void sched_k(
    const int2* __restrict__ gidx, const float2* __restrict__ gw,
    int* __restrict__ tile_expert, int* __restrict__ tile_row0,
    int* __restrict__ rowmap, float* __restrict__ wmap)
{
  __shared__ int cnt[E_NUM];
  __shared__ int pstart[E_NUM + 1];
  const int wid = threadIdx.x >> 6, lane = threadIdx.x & 63;

  // phase 1: count
  int c = 0;
  for (int r0 = 0; r0 < B_ROWS; r0 += 64) {
    int2 g = gidx[r0 + lane];
    c += __popcll(__ballot(g.x == wid)) + __popcll(__ballot(g.y == wid));
  }
  if (lane == 0) cnt[wid] = c;
  __syncthreads();

  // phase 2: padded segment starts + tile table (thread 0; tiny)
  if (threadIdx.x == 0) {
    int acc = 0, t = 0;
    for (int e = 0; e < E_NUM; ++e) {
      pstart[e] = acc;
      const int nt = (cnt[e] + 127) >> 7;
      for (int i = 0; i < nt; ++i) {
        tile_expert[t] = e;
        tile_row0[t] = acc + i * 128;
        ++t;
      }
      acc += nt << 7;
    }
    pstart[E_NUM] = acc;
    for (; t < NT_MAX; ++t) { tile_expert[t] = -1; tile_row0[t] = 0; }
  }
  __syncthreads();

  // phase 3: assignment (wave wid scans all rows, ranks matches via ballot)
  const unsigned long long below = (lane == 0) ? 0ull : ((~0ull) >> (64 - lane));
  int base = pstart[wid];
  for (int r0 = 0; r0 < B_ROWS; r0 += 64) {
    const int r = r0 + lane;
    const int2 g = gidx[r];
    const float2 w = gw[r];
    const unsigned long long m0 = __ballot(g.x == wid);
    const unsigned long long m1 = __ballot(g.y == wid);
    if (g.x == wid) {
      const int p = base + __popcll(m0 & below);
      rowmap[p] = r; wmap[p] = w.x;
    }
    base += __popcll(m0);
    if (g.y == wid) {
      const int p = base + __popcll(m1 & below);
      rowmap[p] = r; wmap[p] = w.y;
    }
    base += __popcll(m1);
  }
  // phase 4: zero pad slots (loads use row 0, stores skipped via w==0)
  for (int p = pstart[wid] + cnt[wid] + lane; p < pstart[wid + 1]; p += 64) {
    rowmap[p] = 0; wmap[p] = 0.f;
  }
}

// ------------------------------------------------------------------ GEMM ----
template <bool GATHER, bool RELU, bool FINAL>
__global__ __launch_bounds__(256) void gemm_k(
    const ushort_t* __restrict__ A,      // GATHER: xb [8192][K]; else z [NPAD][K]
    const ushort_t* __restrict__ B,      // bf16 [E][N][K]
    size_t bEStr,
    const int* __restrict__ tile_expert, const int* __restrict__ tile_row0,
    const int* __restrict__ rowmap, const float* __restrict__ wmap,
    ushort_t* __restrict__ Z,            // mid out [NPAD][H_DIM]
    float* __restrict__ out)             // final out
{
  constexpr int K = 512;
  __shared__ ushort_t lA[128 * 32];
  __shared__ ushort_t lB[128 * 32];
  __shared__ float wrow[128];
  __shared__ int rrow[128];

  const int t = blockIdx.x;
  const int e = tile_expert[t];
  if (e < 0) return;
  const int zr0 = tile_row0[t];
  const int bn0 = blockIdx.y * 128;

  const int tid = threadIdx.x, wid = tid >> 6, lane = tid & 63;
  const int sr = wid * 16 + (lane >> 2);
  const int sc = (lane & 3) * 8;

  const ushort_t* Bb = B + (size_t)e * bEStr + (size_t)bn0 * K;
  const ushort_t* gb = Bb + (size_t)sr * K + sc;
  const ushort_t *ga0, *ga1;
  if (GATHER) {
    ga0 = A + (size_t)rowmap[zr0 + sr] * K + sc;
    ga1 = A + (size_t)rowmap[zr0 + sr + 64] * K + sc;
  } else {
    ga0 = A + (size_t)(zr0 + sr) * K + sc;
    ga1 = ga0 + (size_t)64 * K;
  }
  ushort_t* la = lA + wid * 512;
  ushort_t* lb = lB + wid * 512;

  floatx4 acc[4][4] = {};
  const int wm = (wid >> 1) * 64, wn = (wid & 1) * 64;
  const int fr = lane & 15, q = lane >> 4;

  for (int k0 = 0; k0 < K; k0 += 32) {
    gload_lds16(ga0 + k0, la);
    gload_lds16(ga1 + k0, la + 64 * 32);
    gload_lds16(gb + k0, lb);
    gload_lds16(gb + (size_t)64 * K + k0, lb + 64 * 32);
    __syncthreads();

    bf16x8 af[4], bfr[4];
#pragma unroll
    for (int mi = 0; mi < 4; ++mi)
      af[mi] = *(const bf16x8*)(lA + (wm + mi * 16 + fr) * 32 + q * 8);
#pragma unroll
    for (int ni = 0; ni < 4; ++ni)
      bfr[ni] = *(const bf16x8*)(lB + (wn + ni * 16 + fr) * 32 + q * 8);
#pragma unroll
    for (int mi = 0; mi < 4; ++mi)
#pragma unroll
      for (int ni = 0; ni < 4; ++ni)
        acc[mi][ni] = __builtin_amdgcn_mfma_f32_16x16x32_bf16(
            af[mi], bfr[ni], acc[mi][ni], 0, 0, 0);
    __syncthreads();
  }

  if (!FINAL) {
    // C/D layout: col = lane&15, row = (lane>>4)*4 + reg (m89-verified)
    ushort_t* Zb = Z + (size_t)zr0 * H_DIM + bn0;
#pragma unroll
    for (int mi = 0; mi < 4; ++mi)
#pragma unroll
      for (int r = 0; r < 4; ++r) {
        const int row = wm + mi * 16 + q * 4 + r;
        ushort_t* zr = Zb + (size_t)row * H_DIM + wn + fr;
#pragma unroll
        for (int ni = 0; ni < 4; ++ni) {
          float v = acc[mi][ni][r];
          if (RELU) v = fmaxf(v, 0.0f);
          zr[ni * 16] = f2bf(v);
        }
      }
  } else {
    if (tid < 128) {
      wrow[tid] = wmap[zr0 + tid];
      rrow[tid] = rowmap[zr0 + tid];
    }
    __syncthreads();
#pragma unroll
    for (int mi = 0; mi < 4; ++mi)
#pragma unroll
      for (int r = 0; r < 4; ++r) {
        const int row = wm + mi * 16 + q * 4 + r;
        const float w = wrow[row];
        if (w != 0.0f) {
          const size_t orig = rrow[row];
#pragma unroll
          for (int ni = 0; ni < 4; ++ni) {
            const int col = bn0 + wn + ni * 16 + fr;
            if (col < T_DIM) {
              const float v = acc[mi][ni][r] * w;
              float* dst = (col < I_DIM)
                  ? out + orig * I_DIM + col
                  : out + (size_t)B_ROWS * I_DIM + orig * (T_DIM - I_DIM) +
                        (col - I_DIM);
              atomicAdd(dst, v);
            }
          }
        }
      }
  }
}

// ---------------------------------------------------------------- launch ----
extern "C" void kernel_launch(void* const* d_in, const int* in_sizes, int n_in,
                              void* d_out, int out_size, void* d_ws,
                              size_t ws_size, hipStream_t stream) {
  const float* x     = (const float*)d_in[0];
  const float* gamma = (const float*)d_in[1];
  const float* beta  = (const float*)d_in[2];
  const float* Wg    = (const float*)d_in[3];
  const float* W0    = (const float*)d_in[4];
  const float* Wmid  = (const float*)d_in[5];
  const float* Wout  = (const float*)d_in[6];
  float* out = (float*)d_out;

  char* ws = (char*)d_ws;
  size_t off = 0;
  auto alloc = [&](size_t bytes) -> char* {
    char* p = ws + off;
    off += (bytes + 255) & ~(size_t)255;
    return p;
  };

  const size_t SQ = (size_t)H_DIM * H_DIM;
  ushort_t* xb    = (ushort_t*)alloc((size_t)B_ROWS * I_DIM * 2);
  ushort_t* W0t   = (ushort_t*)alloc((size_t)E_NUM * SQ * 2);
  ushort_t* Wmidt = (ushort_t*)alloc((size_t)3 * E_NUM * SQ * 2);
  ushort_t* Woutt = (ushort_t*)alloc((size_t)E_NUM * T_PAD * H_DIM * 2);
  int2*   gidx = (int2*)alloc((size_t)B_ROWS * sizeof(int2));
  float2* gwv  = (float2*)alloc((size_t)B_ROWS * sizeof(float2));
  int*   te   = (int*)alloc(NT_MAX * sizeof(int));
  int*   tr0  = (int*)alloc(NT_MAX * sizeof(int));
  int*   rmap = (int*)alloc(NPAD * sizeof(int));
  float* wmap = (float*)alloc(NPAD * sizeof(float));
  ushort_t* z0 = (ushort_t*)alloc((size_t)NPAD * H_DIM * 2);
  ushort_t* z1 = (ushort_t*)alloc((size_t)NPAD * H_DIM * 2);

  hipMemsetAsync(d_out, 0, (size_t)out_size * sizeof(float), stream);

  gate_cast_k<<<dim3(B_ROWS / 4), 256, 0, stream>>>(x, gamma, beta, Wg, xb,
                                                    gidx, gwv);
  transpose_cast_k<<<dim3(16, 16, 8), dim3(32, 8), 0, stream>>>(
      W0, W0t, 512, 512, SQ, SQ);
  transpose_cast_k<<<dim3(16, 16, 24), dim3(32, 8), 0, stream>>>(
      Wmid, Wmidt, 512, 512, SQ, SQ);
  transpose_cast_k<<<dim3(19, 16, 8), dim3(32, 8), 0, stream>>>(
      Wout, Woutt, 512, 608, (size_t)512 * 608, (size_t)T_PAD * 512);
  sched_k<<<1, 512, 0, stream>>>(gidx, gwv, te, tr0, rmap, wmap);

  const dim3 gmid(NT_MAX, H_DIM / 128);
  const dim3 gfin(NT_MAX, T_PAD / 128);
  // z0 = gather(x) @ W0   (no relu)
  gemm_k<true, false, false><<<gmid, 256, 0, stream>>>(
      xb, W0t, SQ, te, tr0, rmap, wmap, z0, nullptr);
  // z1 = relu(z0 @ Wmid[0])
  gemm_k<false, true, false><<<gmid, 256, 0, stream>>>(
      z0, Wmidt + 0 * E_NUM * SQ, SQ, te, tr0, rmap, wmap, z1, nullptr);
  // z0 = relu(z1 @ Wmid[1])
  gemm_k<false, true, false><<<gmid, 256, 0, stream>>>(
      z1, Wmidt + 1 * E_NUM * SQ, SQ, te, tr0, rmap, wmap, z0, nullptr);
  // z1 = relu(z0 @ Wmid[2])
  gemm_k<false, true, false><<<gmid, 256, 0, stream>>>(
      z0, Wmidt + 2 * E_NUM * SQ, SQ, te, tr0, rmap, wmap, z1, nullptr);
  // out += gate_w * (z1 @ Wout), scattered + split backcast/forecast
  gemm_k<false, false, true><<<gfin, 256, 0, stream>>>(
      z1, Woutt, (size_t)T_PAD * H_DIM, te, tr0, rmap, wmap, nullptr, out);
}